// Round 1
// baseline (312.687 us; speedup 1.0000x reference)
//
#include <hip/hip_runtime.h>
#include <hip/hip_bf16.h>

// Problem constants
#define BATCH   4
#define S_LEN   2048
#define DMODEL  1024
#define M_TOT   (BATCH * S_LEN)   // 8192
#define N_TOT   DMODEL            // 1024
#define K_TOT   DMODEL            // 1024

// GEMM tile
#define BM 128
#define BN 128
#define BK 32
#define LDK 40   // padded LDS row stride (bf16 elems): 80B rows -> <=2-way bank conflicts

typedef __attribute__((ext_vector_type(8))) short bf16x8;
typedef __attribute__((ext_vector_type(4))) short bf16x4v;
typedef __attribute__((ext_vector_type(4))) float f32x4;

__device__ __forceinline__ short f2bf(float f) {
  union { float f; unsigned int u; } v; v.f = f;
  unsigned int u = v.u;
  u += 0x7fffu + ((u >> 16) & 1u);   // round-to-nearest-even
  return (short)(u >> 16);
}

// ---------------------------------------------------------------------------
// K1: y[m,n] = sum_k x[m,k]*W1[n,k] + (b0[n]+b1[n])
// A = x row-major [M,K]; Bw = W1 row-major [N,K] (B^T-style GEMM)
// ---------------------------------------------------------------------------
__global__ __launch_bounds__(256) void gemm_bias_kernel(
    const float* __restrict__ A, const float* __restrict__ Bw,
    const float* __restrict__ b0, const float* __restrict__ b1,
    float* __restrict__ C) {
  __shared__ short As[2][BM][LDK];
  __shared__ short Bs[2][BM][LDK];

  const int tid  = threadIdx.x;
  const int lane = tid & 63;
  const int w    = tid >> 6;
  const int wm   = w >> 1, wn = w & 1;
  const int bn   = blockIdx.x & 7;        // N/BN = 8
  const int bm   = blockIdx.x >> 3;

  const int l15 = lane & 15;
  const int kc  = (lane >> 4) << 3;       // 0,8,16,24 (k-offset within BK)

  f32x4 acc[4][4];
#pragma unroll
  for (int a = 0; a < 4; a++)
#pragma unroll
    for (int b = 0; b < 4; b++) {
      f32x4 z = {0.f, 0.f, 0.f, 0.f};
      acc[a][b] = z;
    }

  const float* Abase = A  + (size_t)bm * BM * K_TOT;
  const float* Bbase = Bw + (size_t)bn * BN * K_TOT;

  float4 ra[4], rb[4];

#define LOADT(k0)                                                          \
  {                                                                        \
    _Pragma("unroll")                                                      \
    for (int q = 0; q < 4; q++) {                                          \
      int fidx = tid + q * 256;                                            \
      int r = fidx >> 3, cc = (fidx & 7) << 2;                             \
      ra[q] = *(const float4*)(Abase + (size_t)r * K_TOT + (k0) + cc);     \
      rb[q] = *(const float4*)(Bbase + (size_t)r * K_TOT + (k0) + cc);     \
    }                                                                      \
  }

#define STORET(buf)                                                        \
  {                                                                        \
    _Pragma("unroll")                                                      \
    for (int q = 0; q < 4; q++) {                                          \
      int fidx = tid + q * 256;                                            \
      int r = fidx >> 3, cc = (fidx & 7) << 2;                             \
      bf16x4v av = { f2bf(ra[q].x), f2bf(ra[q].y),                         \
                     f2bf(ra[q].z), f2bf(ra[q].w) };                       \
      bf16x4v bv = { f2bf(rb[q].x), f2bf(rb[q].y),                         \
                     f2bf(rb[q].z), f2bf(rb[q].w) };                       \
      *(bf16x4v*)&As[buf][r][cc] = av;                                     \
      *(bf16x4v*)&Bs[buf][r][cc] = bv;                                     \
    }                                                                      \
  }

  LOADT(0);
  STORET(0);
  __syncthreads();

  const int NT = K_TOT / BK;  // 32
  for (int t = 0; t < NT; ++t) {
    const int cur = t & 1;
    if (t + 1 < NT) LOADT((t + 1) * BK);

    bf16x8 af[4], bf[4];
#pragma unroll
    for (int mi = 0; mi < 4; mi++)
      af[mi] = *(const bf16x8*)&As[cur][wm * 64 + mi * 16 + l15][kc];
#pragma unroll
    for (int ni = 0; ni < 4; ni++)
      bf[ni] = *(const bf16x8*)&Bs[cur][wn * 64 + ni * 16 + l15][kc];

#pragma unroll
    for (int mi = 0; mi < 4; mi++)
#pragma unroll
      for (int ni = 0; ni < 4; ni++)
        acc[mi][ni] = __builtin_amdgcn_mfma_f32_16x16x32_bf16(
            af[mi], bf[ni], acc[mi][ni], 0, 0, 0);

    if (t + 1 < NT) STORET(cur ^ 1);
    __syncthreads();
  }

  // Epilogue: C/D layout col=lane&15, row=(lane>>4)*4+r
#pragma unroll
  for (int ni = 0; ni < 4; ni++) {
    const int col = bn * BN + wn * 64 + ni * 16 + l15;
    const float bias = b0[col] + b1[col];
#pragma unroll
    for (int mi = 0; mi < 4; mi++) {
      const int row0 = bm * BM + wm * 64 + mi * 16 + ((lane >> 4) << 2);
#pragma unroll
      for (int r = 0; r < 4; r++)
        C[(size_t)(row0 + r) * N_TOT + col] = acc[mi][ni][r] + bias;
    }
  }
#undef LOADT
#undef STORET
}

// ---------------------------------------------------------------------------
// K2: for each (b,i): find j in [2, i-1] with ids[j-1]==ids[i] &&
// ids[j-2]==ids[i-1]; avg matched x rows; y[b,i,:] += avg @ W0^T
// ---------------------------------------------------------------------------
__global__ __launch_bounds__(256) void induct_kernel(
    const int* __restrict__ ids, const float* __restrict__ x,
    const float* __restrict__ W0, float* __restrict__ y) {
  const int b = blockIdx.x >> 11;        // S=2048
  const int i = blockIdx.x & (S_LEN - 1);
  if (i < 3) return;                     // block-uniform

  const int* idb = ids + b * S_LEN;
  __shared__ int   s_cnt;
  __shared__ int   s_list[S_LEN];
  __shared__ float s_avg[DMODEL];

  const int tid = threadIdx.x;
  if (tid == 0) s_cnt = 0;
  __syncthreads();

  const int ti = idb[i], tp = idb[i - 1];
  for (int j = 2 + tid; j < i; j += 256) {
    if (idb[j - 1] == ti && idb[j - 2] == tp) {
      int p = atomicAdd(&s_cnt, 1);
      s_list[p] = j;
    }
  }
  __syncthreads();
  const int c = s_cnt;
  if (c == 0) return;                    // block-uniform

  // accumulate matched rows (each thread owns 4 consecutive channels)
  float4 s = {0.f, 0.f, 0.f, 0.f};
  const float4* xb = (const float4*)(x + (size_t)b * S_LEN * DMODEL);
  for (int r = 0; r < c; ++r) {
    const int j = s_list[r];
    float4 v = xb[(size_t)j * (DMODEL / 4) + tid];
    s.x += v.x; s.y += v.y; s.z += v.z; s.w += v.w;
  }
  const float inv = 1.0f / (float)c;
  s.x *= inv; s.y *= inv; s.z *= inv; s.w *= inv;
  *(float4*)&s_avg[tid * 4] = s;
  __syncthreads();

  // matvec: y[b,i,n] += sum_k avg[k] * W0[n,k]
  float out[4];
#pragma unroll
  for (int q = 0; q < 4; ++q) {
    const int n = q * 256 + tid;
    const float4* wr = (const float4*)(W0 + (size_t)n * DMODEL);
    float a = 0.f;
    for (int kk = 0; kk < DMODEL / 4; ++kk) {
      float4 wv = wr[kk];
      float4 av = *(const float4*)&s_avg[kk * 4];
      a += wv.x * av.x + wv.y * av.y + wv.z * av.z + wv.w * av.w;
    }
    out[q] = a;
  }
  float* yrow = y + ((size_t)(b * S_LEN + i)) * DMODEL;
#pragma unroll
  for (int q = 0; q < 4; ++q) yrow[q * 256 + tid] += out[q];
}

// ---------------------------------------------------------------------------
extern "C" void kernel_launch(void* const* d_in, const int* in_sizes, int n_in,
                              void* d_out, int out_size, void* d_ws, size_t ws_size,
                              hipStream_t stream) {
  const float* x   = (const float*)d_in[0];
  const int*   ids = (const int*)  d_in[1];
  const float* W0  = (const float*)d_in[2];
  const float* b0  = (const float*)d_in[3];
  const float* W1  = (const float*)d_in[4];
  const float* b1  = (const float*)d_in[5];
  float* y = (float*)d_out;

  // K1: dense y = x @ W1^T + (b0 + b1)
  gemm_bias_kernel<<<(M_TOT / BM) * (N_TOT / BN), 256, 0, stream>>>(x, W1, b0, b1, y);
  // K2: sparse induction correction y += h0 @ W0^T
  induct_kernel<<<BATCH * S_LEN, 256, 0, stream>>>(ids, x, W0, y);
}

// Round 5
// 206.071 us; speedup vs baseline: 1.5174x; 1.5174x over previous
//
#include <hip/hip_runtime.h>
#include <hip/hip_bf16.h>

// Problem constants
#define BATCH   4
#define S_LEN   2048
#define DMODEL  1024
#define M_TOT   (BATCH * S_LEN)   // 8192
#define N_TOT   DMODEL            // 1024
#define K_TOT   DMODEL            // 1024

#define MAXR    2048              // compacted matched-row capacity

// ws layout (byte offsets)
#define CNT_OFF   0
#define ROWS_OFF  1024
#define AVG_OFF   16384                         // MAXR * 4096 bytes
#define XBF_OFF   (10u * 1024u * 1024u)         // 16 MB bf16 x
#define WBF_OFF   (27u * 1024u * 1024u)         // 2 MB bf16 W1
#define FULL_NEED (30u * 1024u * 1024u)
#define MID_NEED  (9u * 1024u * 1024u)

typedef __attribute__((ext_vector_type(8))) short bf16x8;
typedef __attribute__((ext_vector_type(4))) short bf16x4v;
typedef __attribute__((ext_vector_type(4))) float f32x4;

__device__ __forceinline__ short f2bf(float f) {
  union { float f; unsigned int u; } v; v.f = f;
  unsigned int u = v.u;
  u += 0x7fffu + ((u >> 16) & 1u);   // round-to-nearest-even
  return (short)(u >> 16);
}

#define GLOAD(gp, lp)                                               \
  __builtin_amdgcn_global_load_lds(                                 \
      (const __attribute__((address_space(1))) void*)(gp),          \
      (__attribute__((address_space(3))) void*)(lp), 16, 0, 0)

// ---------------------------------------------------------------------------
// init: zero the compaction counter (graph-capture-safe, no memset API)
// ---------------------------------------------------------------------------
__global__ void init_kernel(int* __restrict__ cnt) {
  if (threadIdx.x == 0) *cnt = 0;
}

// ---------------------------------------------------------------------------
// cvt: fp32 -> bf16, 8 elems/thread
// ---------------------------------------------------------------------------
__global__ __launch_bounds__(256) void cvt_kernel(
    const float* __restrict__ in, short* __restrict__ out, int n8) {
  int idx = blockIdx.x * 256 + threadIdx.x;
  if (idx >= n8) return;
  const float4* p = (const float4*)in + (size_t)idx * 2;
  float4 a = p[0], b = p[1];
  bf16x8 v = { f2bf(a.x), f2bf(a.y), f2bf(a.z), f2bf(a.w),
               f2bf(b.x), f2bf(b.y), f2bf(b.z), f2bf(b.w) };
  *(bf16x8*)(out + (size_t)idx * 8) = v;
}

// ---------------------------------------------------------------------------
// m97-structure bf16 GEMM: C[m,n] = sum_k A[m,k]*B[n,k] + (b0[n]+b1[n])
// A,B pre-converted bf16 row-major [*,1024]. 128x128 tile, BK=32,
// global_load_lds width 16, linear LDS, double-buffered.
// ---------------------------------------------------------------------------
__global__ __launch_bounds__(256) void gemm_bf16_kernel(
    const short* __restrict__ Ab, const short* __restrict__ Bb,
    const float* __restrict__ b0, const float* __restrict__ b1,
    float* __restrict__ C) {
  __shared__ short As[2][128 * 32];
  __shared__ short Bs[2][128 * 32];

  const int tid  = threadIdx.x;
  const int lane = tid & 63;
  const int w    = tid >> 6;
  const int wm   = w >> 1, wn = w & 1;

  // bijective XCD swizzle: nwg = 512, 512 % 8 == 0
  const int swz = (blockIdx.x & 7) * 64 + (blockIdx.x >> 3);
  const int bn  = swz & 7, bm = swz >> 3;

  const int l15 = lane & 15;
  const int kc  = (lane >> 4) << 3;      // 0,8,16,24

  const short* Abase = Ab + (size_t)bm * 128 * K_TOT;
  const short* Bbase = Bb + (size_t)bn * 128 * K_TOT;

  const int srow = tid >> 2;             // staging row within 64-row half
  const int scol = (tid & 3) << 3;       // k offset (bf16 elems), 16B each
  const int lbase = (tid & ~63) * 8;     // wave-uniform LDS elem base (+lane*8 by HW)

  f32x4 acc[4][4];
#pragma unroll
  for (int a = 0; a < 4; a++)
#pragma unroll
    for (int b = 0; b < 4; b++) {
      f32x4 z = {0.f, 0.f, 0.f, 0.f};
      acc[a][b] = z;
    }

#define STG(buf, k0)                                                        \
  {                                                                         \
    _Pragma("unroll")                                                       \
    for (int q = 0; q < 2; ++q) {                                           \
      GLOAD(Abase + (size_t)(q * 64 + srow) * K_TOT + (k0) + scol,          \
            &As[buf][q * 2048 + lbase]);                                    \
      GLOAD(Bbase + (size_t)(q * 64 + srow) * K_TOT + (k0) + scol,          \
            &Bs[buf][q * 2048 + lbase]);                                    \
    }                                                                       \
  }

  STG(0, 0);
  __syncthreads();

  const int NT = K_TOT / 32;  // 32
  for (int t = 0; t < NT; ++t) {
    const int cur = t & 1;
    if (t + 1 < NT) STG(cur ^ 1, (t + 1) * 32);

    bf16x8 af[4], bb[4];
#pragma unroll
    for (int mi = 0; mi < 4; ++mi)
      af[mi] = *(const bf16x8*)&As[cur][(wm * 64 + mi * 16 + l15) * 32 + kc];
#pragma unroll
    for (int ni = 0; ni < 4; ++ni)
      bb[ni] = *(const bf16x8*)&Bs[cur][(wn * 64 + ni * 16 + l15) * 32 + kc];

#pragma unroll
    for (int mi = 0; mi < 4; ++mi)
#pragma unroll
      for (int ni = 0; ni < 4; ++ni)
        acc[mi][ni] = __builtin_amdgcn_mfma_f32_16x16x32_bf16(
            af[mi], bb[ni], acc[mi][ni], 0, 0, 0);

    __syncthreads();   // drains vmcnt+lgkm; staged buffer ready, reads done
  }
#undef STG

#pragma unroll
  for (int ni = 0; ni < 4; ni++) {
    const int col = bn * 128 + wn * 64 + ni * 16 + l15;
    const float bias = b0[col] + b1[col];
#pragma unroll
    for (int mi = 0; mi < 4; mi++) {
      const int row0 = bm * 128 + wm * 64 + mi * 16 + ((lane >> 4) << 2);
#pragma unroll
      for (int r = 0; r < 4; r++)
        C[(size_t)(row0 + r) * N_TOT + col] = acc[mi][ni][r] + bias;
    }
  }
}

// ---------------------------------------------------------------------------
// fp32-staging GEMM fallback (round-1 kernel, validated)
// ---------------------------------------------------------------------------
#define BM 128
#define BN 128
#define BK 32
#define LDK 40

__global__ __launch_bounds__(256) void gemm_bias_kernel(
    const float* __restrict__ A, const float* __restrict__ Bw,
    const float* __restrict__ b0, const float* __restrict__ b1,
    float* __restrict__ C) {
  __shared__ short As[2][BM][LDK];
  __shared__ short Bs[2][BM][LDK];

  const int tid  = threadIdx.x;
  const int lane = tid & 63;
  const int w    = tid >> 6;
  const int wm   = w >> 1, wn = w & 1;
  const int bn   = blockIdx.x & 7;
  const int bm   = blockIdx.x >> 3;
  const int l15 = lane & 15;
  const int kc  = (lane >> 4) << 3;

  f32x4 acc[4][4];
#pragma unroll
  for (int a = 0; a < 4; a++)
#pragma unroll
    for (int b = 0; b < 4; b++) {
      f32x4 z = {0.f, 0.f, 0.f, 0.f};
      acc[a][b] = z;
    }

  const float* Abase = A  + (size_t)bm * BM * K_TOT;
  const float* Bbase = Bw + (size_t)bn * BN * K_TOT;
  float4 ra[4], rb[4];

#define LOADT(k0)                                                          \
  {                                                                        \
    _Pragma("unroll")                                                      \
    for (int q = 0; q < 4; q++) {                                          \
      int fidx = tid + q * 256;                                            \
      int r = fidx >> 3, cc = (fidx & 7) << 2;                             \
      ra[q] = *(const float4*)(Abase + (size_t)r * K_TOT + (k0) + cc);     \
      rb[q] = *(const float4*)(Bbase + (size_t)r * K_TOT + (k0) + cc);     \
    }                                                                      \
  }
#define STORET(buf)                                                        \
  {                                                                        \
    _Pragma("unroll")                                                      \
    for (int q = 0; q < 4; q++) {                                          \
      int fidx = tid + q * 256;                                            \
      int r = fidx >> 3, cc = (fidx & 7) << 2;                             \
      bf16x4v av = { f2bf(ra[q].x), f2bf(ra[q].y),                         \
                     f2bf(ra[q].z), f2bf(ra[q].w) };                       \
      bf16x4v bv = { f2bf(rb[q].x), f2bf(rb[q].y),                         \
                     f2bf(rb[q].z), f2bf(rb[q].w) };                       \
      *(bf16x4v*)&As[buf][r][cc] = av;                                     \
      *(bf16x4v*)&Bs[buf][r][cc] = bv;                                     \
    }                                                                      \
  }

  LOADT(0);
  STORET(0);
  __syncthreads();

  const int NT = K_TOT / BK;
  for (int t = 0; t < NT; ++t) {
    const int cur = t & 1;
    if (t + 1 < NT) LOADT((t + 1) * BK);
    bf16x8 af[4], bf_[4];
#pragma unroll
    for (int mi = 0; mi < 4; mi++)
      af[mi] = *(const bf16x8*)&As[cur][wm * 64 + mi * 16 + l15][kc];
#pragma unroll
    for (int ni = 0; ni < 4; ni++)
      bf_[ni] = *(const bf16x8*)&Bs[cur][wn * 64 + ni * 16 + l15][kc];
#pragma unroll
    for (int mi = 0; mi < 4; mi++)
#pragma unroll
      for (int ni = 0; ni < 4; ni++)
        acc[mi][ni] = __builtin_amdgcn_mfma_f32_16x16x32_bf16(
            af[mi], bf_[ni], acc[mi][ni], 0, 0, 0);
    if (t + 1 < NT) STORET(cur ^ 1);
    __syncthreads();
  }
#undef LOADT
#undef STORET

#pragma unroll
  for (int ni = 0; ni < 4; ni++) {
    const int col = bn * BN + wn * 64 + ni * 16 + l15;
    const float bias = b0[col] + b1[col];
#pragma unroll
    for (int mi = 0; mi < 4; mi++) {
      const int row0 = bm * BM + wm * 64 + mi * 16 + ((lane >> 4) << 2);
#pragma unroll
      for (int r = 0; r < 4; r++)
        C[(size_t)(row0 + r) * N_TOT + col] = acc[mi][ni][r] + bias;
    }
  }
}

// ---------------------------------------------------------------------------
// K2a scan: per (b,i) find bigram matches, average matched x rows,
// append (row_id, avg) to compact list in ws. Overflow -> direct atomic matvec.
// ---------------------------------------------------------------------------
__global__ __launch_bounds__(256) void scan_kernel(
    const int* __restrict__ ids, const float* __restrict__ x,
    int* __restrict__ cnt, int* __restrict__ rows, float* __restrict__ avg,
    const float* __restrict__ W0, float* __restrict__ y) {
  const int b = blockIdx.x >> 11;
  const int i = blockIdx.x & (S_LEN - 1);
  if (i < 3) return;

  const int* idb = ids + b * S_LEN;
  __shared__ int   s_cnt;
  __shared__ int   s_slot;
  __shared__ int   s_list[S_LEN];
  __shared__ float s_avg[DMODEL];

  const int tid = threadIdx.x;
  if (tid == 0) s_cnt = 0;
  __syncthreads();

  const int ti = idb[i], tp = idb[i - 1];
  for (int j = 2 + tid; j < i; j += 256) {
    if (idb[j - 1] == ti && idb[j - 2] == tp) {
      int p = atomicAdd(&s_cnt, 1);
      s_list[p] = j;
    }
  }
  __syncthreads();
  const int c = s_cnt;
  if (c == 0) return;

  float4 s = {0.f, 0.f, 0.f, 0.f};
  const float4* xb = (const float4*)(x + (size_t)b * S_LEN * DMODEL);
  for (int r = 0; r < c; ++r) {
    const int j = s_list[r];
    float4 v = xb[(size_t)j * (DMODEL / 4) + tid];
    s.x += v.x; s.y += v.y; s.z += v.z; s.w += v.w;
  }
  const float inv = 1.0f / (float)c;
  s.x *= inv; s.y *= inv; s.z *= inv; s.w *= inv;

  if (tid == 0) s_slot = atomicAdd(cnt, 1);
  __syncthreads();
  const int slot = s_slot;

  if (slot < MAXR) {
    if (tid == 0) rows[slot] = b * S_LEN + i;
    *(float4*)(avg + (size_t)slot * DMODEL + tid * 4) = s;
  } else {
    // overflow fallback: direct matvec, atomic accumulate (runs after GEMM)
    *(float4*)&s_avg[tid * 4] = s;
    __syncthreads();
    float* yrow = y + ((size_t)(b * S_LEN + i)) * DMODEL;
#pragma unroll
    for (int q = 0; q < 4; ++q) {
      const int n = q * 256 + tid;
      const float4* wr = (const float4*)(W0 + (size_t)n * DMODEL);
      float a = 0.f;
      for (int kk = 0; kk < DMODEL / 4; ++kk) {
        float4 wv = wr[kk];
        float4 av = *(const float4*)&s_avg[kk * 4];
        a += wv.x * av.x + wv.y * av.y + wv.z * av.z + wv.w * av.w;
      }
      atomicAdd(&yrow[n], a);
    }
  }
}

// ---------------------------------------------------------------------------
// K2b apply: y[rows[r], :] += avg[r] @ W0^T  — streams W0 exactly once.
// 64 blocks x 256 threads; block handles 16 output cols; 16 threads/col.
// ---------------------------------------------------------------------------
__global__ __launch_bounds__(256) void apply_kernel(
    const int* __restrict__ cnt, const int* __restrict__ rows,
    const float* __restrict__ avg, const float* __restrict__ W0,
    float* __restrict__ y) {
  int R = *cnt; if (R > MAXR) R = MAXR;
  if (R == 0) return;
  const int t = threadIdx.x;
  const int n = blockIdx.x * 16 + (t >> 4);
  const int kseg = t & 15;   // 64 floats each
  const float4* wr = (const float4*)(W0 + (size_t)n * DMODEL + kseg * 64);

  for (int r = 0; r < R; ++r) {
    const float4* ar = (const float4*)(avg + (size_t)r * DMODEL + kseg * 64);
    float a = 0.f;
#pragma unroll
    for (int u = 0; u < 16; ++u) {
      float4 wv = wr[u], av = ar[u];
      a += wv.x * av.x + wv.y * av.y + wv.z * av.z + wv.w * av.w;
    }
#pragma unroll
    for (int s = 8; s >= 1; s >>= 1) a += __shfl_down(a, s, 16);
    if (kseg == 0) {
      const int m = rows[r];
      y[(size_t)m * DMODEL + n] += a;
    }
  }
}

// ---------------------------------------------------------------------------
// round-1 induct kernel (ultra fallback, tiny ws)
// ---------------------------------------------------------------------------
__global__ __launch_bounds__(256) void induct_kernel(
    const int* __restrict__ ids, const float* __restrict__ x,
    const float* __restrict__ W0, float* __restrict__ y) {
  const int b = blockIdx.x >> 11;
  const int i = blockIdx.x & (S_LEN - 1);
  if (i < 3) return;
  const int* idb = ids + b * S_LEN;
  __shared__ int   s_cnt;
  __shared__ int   s_list[S_LEN];
  __shared__ float s_avg[DMODEL];
  const int tid = threadIdx.x;
  if (tid == 0) s_cnt = 0;
  __syncthreads();
  const int ti = idb[i], tp = idb[i - 1];
  for (int j = 2 + tid; j < i; j += 256) {
    if (idb[j - 1] == ti && idb[j - 2] == tp) {
      int p = atomicAdd(&s_cnt, 1);
      s_list[p] = j;
    }
  }
  __syncthreads();
  const int c = s_cnt;
  if (c == 0) return;
  float4 s = {0.f, 0.f, 0.f, 0.f};
  const float4* xb = (const float4*)(x + (size_t)b * S_LEN * DMODEL);
  for (int r = 0; r < c; ++r) {
    const int j = s_list[r];
    float4 v = xb[(size_t)j * (DMODEL / 4) + tid];
    s.x += v.x; s.y += v.y; s.z += v.z; s.w += v.w;
  }
  const float inv = 1.0f / (float)c;
  s.x *= inv; s.y *= inv; s.z *= inv; s.w *= inv;
  *(float4*)&s_avg[tid * 4] = s;
  __syncthreads();
  float out[4];
#pragma unroll
  for (int q = 0; q < 4; ++q) {
    const int n = q * 256 + tid;
    const float4* wr = (const float4*)(W0 + (size_t)n * DMODEL);
    float a = 0.f;
    for (int kk = 0; kk < DMODEL / 4; ++kk) {
      float4 wv = wr[kk];
      float4 av = *(const float4*)&s_avg[kk * 4];
      a += wv.x * av.x + wv.y * av.y + wv.z * av.z + wv.w * av.w;
    }
    out[q] = a;
  }
  float* yrow = y + ((size_t)(b * S_LEN + i)) * DMODEL;
#pragma unroll
  for (int q = 0; q < 4; ++q) yrow[q * 256 + tid] += out[q];
}

// ---------------------------------------------------------------------------
extern "C" void kernel_launch(void* const* d_in, const int* in_sizes, int n_in,
                              void* d_out, int out_size, void* d_ws, size_t ws_size,
                              hipStream_t stream) {
  const float* x   = (const float*)d_in[0];
  const int*   ids = (const int*)  d_in[1];
  const float* W0  = (const float*)d_in[2];
  const float* b0  = (const float*)d_in[3];
  const float* W1  = (const float*)d_in[4];
  const float* b1  = (const float*)d_in[5];
  float* y = (float*)d_out;

  char* ws = (char*)d_ws;
  int*   cnt  = (int*)(ws + CNT_OFF);
  int*   rows = (int*)(ws + ROWS_OFF);
  float* avg  = (float*)(ws + AVG_OFF);
  short* xbf  = (short*)(ws + XBF_OFF);
  short* wbf  = (short*)(ws + WBF_OFF);

  const bool full = ws_size >= FULL_NEED;
  const bool mid  = ws_size >= MID_NEED;

  if (full) {
    cvt_kernel<<<(M_TOT * K_TOT / 8 + 255) / 256, 256, 0, stream>>>(x, xbf, M_TOT * K_TOT / 8);
    cvt_kernel<<<(N_TOT * K_TOT / 8 + 255) / 256, 256, 0, stream>>>(W1, wbf, N_TOT * K_TOT / 8);
    gemm_bf16_kernel<<<(M_TOT / 128) * (N_TOT / 128), 256, 0, stream>>>(xbf, wbf, b0, b1, y);
  } else {
    gemm_bias_kernel<<<(M_TOT / BM) * (N_TOT / BN), 256, 0, stream>>>(x, W1, b0, b1, y);
  }

  if (mid) {
    init_kernel<<<1, 64, 0, stream>>>(cnt);
    scan_kernel<<<BATCH * S_LEN, 256, 0, stream>>>(ids, x, cnt, rows, avg, W0, y);
    apply_kernel<<<64, 256, 0, stream>>>(cnt, rows, avg, W0, y);
  } else {
    induct_kernel<<<BATCH * S_LEN, 256, 0, stream>>>(ids, x, W0, y);
  }
}

// Round 6
// 166.641 us; speedup vs baseline: 1.8764x; 1.2366x over previous
//
#include <hip/hip_runtime.h>
#include <hip/hip_bf16.h>

// Problem constants
#define BATCH   4
#define S_LEN   2048
#define DMODEL  1024
#define M_TOT   (BATCH * S_LEN)   // 8192
#define N_TOT   DMODEL            // 1024
#define K_TOT   DMODEL            // 1024

#define MAXR    2048              // compacted matched-row capacity
#define RSLOTS  256               // apply-kernel r-parallelism

// ws layout (byte offsets)
#define CNT_OFF   0
#define ROWS_OFF  1024
#define AVG_OFF   16384                         // MAXR * 4096 bytes
#define XBF_OFF   (10u * 1024u * 1024u)         // 16 MB bf16 x
#define WBF_OFF   (27u * 1024u * 1024u)         // 2 MB bf16 W1
#define FULL_NEED (30u * 1024u * 1024u)
#define MID_NEED  (9u * 1024u * 1024u)

typedef __attribute__((ext_vector_type(8))) short bf16x8;
typedef __attribute__((ext_vector_type(4))) short bf16x4v;
typedef __attribute__((ext_vector_type(4))) float f32x4;

__device__ __forceinline__ short f2bf(float f) {
  union { float f; unsigned int u; } v; v.f = f;
  unsigned int u = v.u;
  u += 0x7fffu + ((u >> 16) & 1u);   // round-to-nearest-even
  return (short)(u >> 16);
}

#define GLOAD(gp, lp)                                               \
  __builtin_amdgcn_global_load_lds(                                 \
      (const __attribute__((address_space(1))) void*)(gp),          \
      (__attribute__((address_space(3))) void*)(lp), 16, 0, 0)

// ---------------------------------------------------------------------------
// init: zero the compaction counter (graph-capture-safe, no memset API)
// ---------------------------------------------------------------------------
__global__ void init_kernel(int* __restrict__ cnt) {
  if (threadIdx.x == 0) *cnt = 0;
}

// ---------------------------------------------------------------------------
// cvt: fp32 -> bf16, 8 elems/thread
// ---------------------------------------------------------------------------
__global__ __launch_bounds__(256) void cvt_kernel(
    const float* __restrict__ in, short* __restrict__ out, int n8) {
  int idx = blockIdx.x * 256 + threadIdx.x;
  if (idx >= n8) return;
  const float4* p = (const float4*)in + (size_t)idx * 2;
  float4 a = p[0], b = p[1];
  bf16x8 v = { f2bf(a.x), f2bf(a.y), f2bf(a.z), f2bf(a.w),
               f2bf(b.x), f2bf(b.y), f2bf(b.z), f2bf(b.w) };
  *(bf16x8*)(out + (size_t)idx * 8) = v;
}

// ---------------------------------------------------------------------------
// m97-structure bf16 GEMM: C[m,n] = sum_k A[m,k]*B[n,k] + (b0[n]+b1[n])
// A,B pre-converted bf16 row-major [*,1024]. 128x128 tile, BK=32,
// global_load_lds width 16, linear LDS, double-buffered.
// ---------------------------------------------------------------------------
__global__ __launch_bounds__(256) void gemm_bf16_kernel(
    const short* __restrict__ Ab, const short* __restrict__ Bb,
    const float* __restrict__ b0, const float* __restrict__ b1,
    float* __restrict__ C) {
  __shared__ short As[2][128 * 32];
  __shared__ short Bs[2][128 * 32];

  const int tid  = threadIdx.x;
  const int lane = tid & 63;
  const int w    = tid >> 6;
  const int wm   = w >> 1, wn = w & 1;

  // bijective XCD swizzle: nwg = 512, 512 % 8 == 0
  const int swz = (blockIdx.x & 7) * 64 + (blockIdx.x >> 3);
  const int bn  = swz & 7, bm = swz >> 3;

  const int l15 = lane & 15;
  const int kc  = (lane >> 4) << 3;      // 0,8,16,24

  const short* Abase = Ab + (size_t)bm * 128 * K_TOT;
  const short* Bbase = Bb + (size_t)bn * 128 * K_TOT;

  const int srow = tid >> 2;             // staging row within 64-row half
  const int scol = (tid & 3) << 3;       // k offset (bf16 elems), 16B each
  const int lbase = (tid & ~63) * 8;     // wave-uniform LDS elem base (+lane*8 by HW)

  f32x4 acc[4][4];
#pragma unroll
  for (int a = 0; a < 4; a++)
#pragma unroll
    for (int b = 0; b < 4; b++) {
      f32x4 z = {0.f, 0.f, 0.f, 0.f};
      acc[a][b] = z;
    }

#define STG(buf, k0)                                                        \
  {                                                                         \
    _Pragma("unroll")                                                       \
    for (int q = 0; q < 2; ++q) {                                           \
      GLOAD(Abase + (size_t)(q * 64 + srow) * K_TOT + (k0) + scol,          \
            &As[buf][q * 2048 + lbase]);                                    \
      GLOAD(Bbase + (size_t)(q * 64 + srow) * K_TOT + (k0) + scol,          \
            &Bs[buf][q * 2048 + lbase]);                                    \
    }                                                                       \
  }

  STG(0, 0);
  __syncthreads();

  const int NT = K_TOT / 32;  // 32
  for (int t = 0; t < NT; ++t) {
    const int cur = t & 1;
    if (t + 1 < NT) STG(cur ^ 1, (t + 1) * 32);

    bf16x8 af[4], bb[4];
#pragma unroll
    for (int mi = 0; mi < 4; ++mi)
      af[mi] = *(const bf16x8*)&As[cur][(wm * 64 + mi * 16 + l15) * 32 + kc];
#pragma unroll
    for (int ni = 0; ni < 4; ++ni)
      bb[ni] = *(const bf16x8*)&Bs[cur][(wn * 64 + ni * 16 + l15) * 32 + kc];

#pragma unroll
    for (int mi = 0; mi < 4; ++mi)
#pragma unroll
      for (int ni = 0; ni < 4; ++ni)
        acc[mi][ni] = __builtin_amdgcn_mfma_f32_16x16x32_bf16(
            af[mi], bb[ni], acc[mi][ni], 0, 0, 0);

    __syncthreads();   // drains vmcnt+lgkm; staged buffer ready, reads done
  }
#undef STG

#pragma unroll
  for (int ni = 0; ni < 4; ni++) {
    const int col = bn * 128 + wn * 64 + ni * 16 + l15;
    const float bias = b0[col] + b1[col];
#pragma unroll
    for (int mi = 0; mi < 4; mi++) {
      const int row0 = bm * 128 + wm * 64 + mi * 16 + ((lane >> 4) << 2);
#pragma unroll
      for (int r = 0; r < 4; r++)
        C[(size_t)(row0 + r) * N_TOT + col] = acc[mi][ni][r] + bias;
    }
  }
}

// ---------------------------------------------------------------------------
// fp32-staging GEMM fallback (round-1 kernel, validated)
// ---------------------------------------------------------------------------
#define BM 128
#define BN 128
#define BK 32
#define LDK 40

__global__ __launch_bounds__(256) void gemm_bias_kernel(
    const float* __restrict__ A, const float* __restrict__ Bw,
    const float* __restrict__ b0, const float* __restrict__ b1,
    float* __restrict__ C) {
  __shared__ short As[2][BM][LDK];
  __shared__ short Bs[2][BM][LDK];

  const int tid  = threadIdx.x;
  const int lane = tid & 63;
  const int w    = tid >> 6;
  const int wm   = w >> 1, wn = w & 1;
  const int bn   = blockIdx.x & 7;
  const int bm   = blockIdx.x >> 3;
  const int l15 = lane & 15;
  const int kc  = (lane >> 4) << 3;

  f32x4 acc[4][4];
#pragma unroll
  for (int a = 0; a < 4; a++)
#pragma unroll
    for (int b = 0; b < 4; b++) {
      f32x4 z = {0.f, 0.f, 0.f, 0.f};
      acc[a][b] = z;
    }

  const float* Abase = A  + (size_t)bm * BM * K_TOT;
  const float* Bbase = Bw + (size_t)bn * BN * K_TOT;
  float4 ra[4], rb[4];

#define LOADT(k0)                                                          \
  {                                                                        \
    _Pragma("unroll")                                                      \
    for (int q = 0; q < 4; q++) {                                          \
      int fidx = tid + q * 256;                                            \
      int r = fidx >> 3, cc = (fidx & 7) << 2;                             \
      ra[q] = *(const float4*)(Abase + (size_t)r * K_TOT + (k0) + cc);     \
      rb[q] = *(const float4*)(Bbase + (size_t)r * K_TOT + (k0) + cc);     \
    }                                                                      \
  }
#define STORET(buf)                                                        \
  {                                                                        \
    _Pragma("unroll")                                                      \
    for (int q = 0; q < 4; q++) {                                          \
      int fidx = tid + q * 256;                                            \
      int r = fidx >> 3, cc = (fidx & 7) << 2;                             \
      bf16x4v av = { f2bf(ra[q].x), f2bf(ra[q].y),                         \
                     f2bf(ra[q].z), f2bf(ra[q].w) };                       \
      bf16x4v bv = { f2bf(rb[q].x), f2bf(rb[q].y),                         \
                     f2bf(rb[q].z), f2bf(rb[q].w) };                       \
      *(bf16x4v*)&As[buf][r][cc] = av;                                     \
      *(bf16x4v*)&Bs[buf][r][cc] = bv;                                     \
    }                                                                      \
  }

  LOADT(0);
  STORET(0);
  __syncthreads();

  const int NT = K_TOT / BK;
  for (int t = 0; t < NT; ++t) {
    const int cur = t & 1;
    if (t + 1 < NT) LOADT((t + 1) * BK);
    bf16x8 af[4], bf_[4];
#pragma unroll
    for (int mi = 0; mi < 4; mi++)
      af[mi] = *(const bf16x8*)&As[cur][wm * 64 + mi * 16 + l15][kc];
#pragma unroll
    for (int ni = 0; ni < 4; ni++)
      bf_[ni] = *(const bf16x8*)&Bs[cur][wn * 64 + ni * 16 + l15][kc];
#pragma unroll
    for (int mi = 0; mi < 4; mi++)
#pragma unroll
      for (int ni = 0; ni < 4; ni++)
        acc[mi][ni] = __builtin_amdgcn_mfma_f32_16x16x32_bf16(
            af[mi], bf_[ni], acc[mi][ni], 0, 0, 0);
    if (t + 1 < NT) STORET(cur ^ 1);
    __syncthreads();
  }
#undef LOADT
#undef STORET

#pragma unroll
  for (int ni = 0; ni < 4; ni++) {
    const int col = bn * BN + wn * 64 + ni * 16 + l15;
    const float bias = b0[col] + b1[col];
#pragma unroll
    for (int mi = 0; mi < 4; mi++) {
      const int row0 = bm * BM + wm * 64 + mi * 16 + ((lane >> 4) << 2);
#pragma unroll
      for (int r = 0; r < 4; r++)
        C[(size_t)(row0 + r) * N_TOT + col] = acc[mi][ni][r] + bias;
    }
  }
}

// ---------------------------------------------------------------------------
// K2a scan: per (b,i) find bigram matches, average matched x rows,
// append (row_id, avg) to compact list in ws. Overflow -> direct atomic matvec.
// ---------------------------------------------------------------------------
__global__ __launch_bounds__(256) void scan_kernel(
    const int* __restrict__ ids, const float* __restrict__ x,
    int* __restrict__ cnt, int* __restrict__ rows, float* __restrict__ avg,
    const float* __restrict__ W0, float* __restrict__ y) {
  const int b = blockIdx.x >> 11;
  const int i = blockIdx.x & (S_LEN - 1);
  if (i < 3) return;

  const int* idb = ids + b * S_LEN;
  __shared__ int   s_cnt;
  __shared__ int   s_slot;
  __shared__ int   s_list[S_LEN];
  __shared__ float s_avg[DMODEL];

  const int tid = threadIdx.x;
  if (tid == 0) s_cnt = 0;
  __syncthreads();

  const int ti = idb[i], tp = idb[i - 1];
  for (int j = 2 + tid; j < i; j += 256) {
    if (idb[j - 1] == ti && idb[j - 2] == tp) {
      int p = atomicAdd(&s_cnt, 1);
      s_list[p] = j;
    }
  }
  __syncthreads();
  const int c = s_cnt;
  if (c == 0) return;

  float4 s = {0.f, 0.f, 0.f, 0.f};
  const float4* xb = (const float4*)(x + (size_t)b * S_LEN * DMODEL);
  for (int r = 0; r < c; ++r) {
    const int j = s_list[r];
    float4 v = xb[(size_t)j * (DMODEL / 4) + tid];
    s.x += v.x; s.y += v.y; s.z += v.z; s.w += v.w;
  }
  const float inv = 1.0f / (float)c;
  s.x *= inv; s.y *= inv; s.z *= inv; s.w *= inv;

  if (tid == 0) s_slot = atomicAdd(cnt, 1);
  __syncthreads();
  const int slot = s_slot;

  if (slot < MAXR) {
    if (tid == 0) rows[slot] = b * S_LEN + i;
    *(float4*)(avg + (size_t)slot * DMODEL + tid * 4) = s;
  } else {
    // overflow fallback: direct matvec, atomic accumulate (runs after GEMM)
    *(float4*)&s_avg[tid * 4] = s;
    __syncthreads();
    float* yrow = y + ((size_t)(b * S_LEN + i)) * DMODEL;
#pragma unroll
    for (int q = 0; q < 4; ++q) {
      const int n = q * 256 + tid;
      const float4* wr = (const float4*)(W0 + (size_t)n * DMODEL);
      float a = 0.f;
      for (int kk = 0; kk < DMODEL / 4; ++kk) {
        float4 wv = wr[kk];
        float4 av = *(const float4*)&s_avg[kk * 4];
        a += wv.x * av.x + wv.y * av.y + wv.z * av.z + wv.w * av.w;
      }
      atomicAdd(&yrow[n], a);
    }
  }
}

// ---------------------------------------------------------------------------
// K2b apply (v2): one block per (r-slot, col-group of 256).
// Block stages avg[r] in LDS; each thread computes one full dot
// W0[n,:]·avg[r] (256 independent float4 loads, pipelined) and does one +=.
// Each (row,col) owned by exactly one block -> plain read-modify-write.
// ---------------------------------------------------------------------------
__global__ __launch_bounds__(256) void apply_kernel(
    const int* __restrict__ cnt, const int* __restrict__ rows,
    const float* __restrict__ avg, const float* __restrict__ W0,
    float* __restrict__ y) {
  int R = *cnt; if (R > MAXR) R = MAXR;
  const int rslot = blockIdx.x >> 2;         // 0..RSLOTS-1
  if (rslot >= R) return;                    // block-uniform early exit
  const int cg = blockIdx.x & 3;             // col group: 256 cols each
  const int tid = threadIdx.x;

  __shared__ float s_avg[DMODEL];

  for (int r = rslot; r < R; r += RSLOTS) {
    if (r != rslot) __syncthreads();         // protect LDS reuse
    *(float4*)&s_avg[tid * 4] =
        *(const float4*)(avg + (size_t)r * DMODEL + tid * 4);
    __syncthreads();

    const int n = cg * 256 + tid;
    const float4* wr = (const float4*)(W0 + (size_t)n * DMODEL);
    float a = 0.f;
#pragma unroll 8
    for (int kk = 0; kk < DMODEL / 4; ++kk) {
      float4 wv = wr[kk];
      float4 av = *(const float4*)&s_avg[kk * 4];
      a += wv.x * av.x + wv.y * av.y + wv.z * av.z + wv.w * av.w;
    }
    const int m = rows[r];
    y[(size_t)m * DMODEL + n] += a;
  }
}

// ---------------------------------------------------------------------------
// round-1 induct kernel (ultra fallback, tiny ws)
// ---------------------------------------------------------------------------
__global__ __launch_bounds__(256) void induct_kernel(
    const int* __restrict__ ids, const float* __restrict__ x,
    const float* __restrict__ W0, float* __restrict__ y) {
  const int b = blockIdx.x >> 11;
  const int i = blockIdx.x & (S_LEN - 1);
  if (i < 3) return;
  const int* idb = ids + b * S_LEN;
  __shared__ int   s_cnt;
  __shared__ int   s_list[S_LEN];
  __shared__ float s_avg[DMODEL];
  const int tid = threadIdx.x;
  if (tid == 0) s_cnt = 0;
  __syncthreads();
  const int ti = idb[i], tp = idb[i - 1];
  for (int j = 2 + tid; j < i; j += 256) {
    if (idb[j - 1] == ti && idb[j - 2] == tp) {
      int p = atomicAdd(&s_cnt, 1);
      s_list[p] = j;
    }
  }
  __syncthreads();
  const int c = s_cnt;
  if (c == 0) return;
  float4 s = {0.f, 0.f, 0.f, 0.f};
  const float4* xb = (const float4*)(x + (size_t)b * S_LEN * DMODEL);
  for (int r = 0; r < c; ++r) {
    const int j = s_list[r];
    float4 v = xb[(size_t)j * (DMODEL / 4) + tid];
    s.x += v.x; s.y += v.y; s.z += v.z; s.w += v.w;
  }
  const float inv = 1.0f / (float)c;
  s.x *= inv; s.y *= inv; s.z *= inv; s.w *= inv;
  *(float4*)&s_avg[tid * 4] = s;
  __syncthreads();
  float out[4];
#pragma unroll
  for (int q = 0; q < 4; ++q) {
    const int n = q * 256 + tid;
    const float4* wr = (const float4*)(W0 + (size_t)n * DMODEL);
    float a = 0.f;
    for (int kk = 0; kk < DMODEL / 4; ++kk) {
      float4 wv = wr[kk];
      float4 av = *(const float4*)&s_avg[kk * 4];
      a += wv.x * av.x + wv.y * av.y + wv.z * av.z + wv.w * av.w;
    }
    out[q] = a;
  }
  float* yrow = y + ((size_t)(b * S_LEN + i)) * DMODEL;
#pragma unroll
  for (int q = 0; q < 4; ++q) yrow[q * 256 + tid] += out[q];
}

// ---------------------------------------------------------------------------
extern "C" void kernel_launch(void* const* d_in, const int* in_sizes, int n_in,
                              void* d_out, int out_size, void* d_ws, size_t ws_size,
                              hipStream_t stream) {
  const float* x   = (const float*)d_in[0];
  const int*   ids = (const int*)  d_in[1];
  const float* W0  = (const float*)d_in[2];
  const float* b0  = (const float*)d_in[3];
  const float* W1  = (const float*)d_in[4];
  const float* b1  = (const float*)d_in[5];
  float* y = (float*)d_out;

  char* ws = (char*)d_ws;
  int*   cnt  = (int*)(ws + CNT_OFF);
  int*   rows = (int*)(ws + ROWS_OFF);
  float* avg  = (float*)(ws + AVG_OFF);
  short* xbf  = (short*)(ws + XBF_OFF);
  short* wbf  = (short*)(ws + WBF_OFF);

  const bool full = ws_size >= FULL_NEED;
  const bool mid  = ws_size >= MID_NEED;

  if (full) {
    cvt_kernel<<<(M_TOT * K_TOT / 8 + 255) / 256, 256, 0, stream>>>(x, xbf, M_TOT * K_TOT / 8);
    cvt_kernel<<<(N_TOT * K_TOT / 8 + 255) / 256, 256, 0, stream>>>(W1, wbf, N_TOT * K_TOT / 8);
    gemm_bf16_kernel<<<(M_TOT / 128) * (N_TOT / 128), 256, 0, stream>>>(xbf, wbf, b0, b1, y);
  } else {
    gemm_bias_kernel<<<(M_TOT / BM) * (N_TOT / BN), 256, 0, stream>>>(x, W1, b0, b1, y);
  }

  if (mid) {
    init_kernel<<<1, 64, 0, stream>>>(cnt);
    scan_kernel<<<BATCH * S_LEN, 256, 0, stream>>>(ids, x, cnt, rows, avg, W0, y);
    apply_kernel<<<RSLOTS * 4, 256, 0, stream>>>(cnt, rows, avg, W0, y);
  } else {
    induct_kernel<<<BATCH * S_LEN, 256, 0, stream>>>(ids, x, W0, y);
  }
}

// Round 7
// 146.602 us; speedup vs baseline: 2.1329x; 1.1367x over previous
//
#include <hip/hip_runtime.h>
#include <hip/hip_bf16.h>

// Problem constants
#define BATCH   4
#define S_LEN   2048
#define DMODEL  1024
#define M_TOT   (BATCH * S_LEN)   // 8192
#define N_TOT   DMODEL            // 1024
#define K_TOT   DMODEL            // 1024

#define MAXR    2048              // compacted matched-row capacity
#define RSLOTS  256               // apply-kernel r-parallelism

// ws layout (byte offsets)
#define CNT_OFF   0
#define ROWS_OFF  1024
#define AVG_OFF   16384                         // MAXR * 4096 bytes
#define XBF_OFF   (10u * 1024u * 1024u)         // 16 MB bf16 x
#define WBF_OFF   (27u * 1024u * 1024u)         // 2 MB bf16 W1
#define FULL_NEED (30u * 1024u * 1024u)
#define MID_NEED  (9u * 1024u * 1024u)

typedef __attribute__((ext_vector_type(8))) short bf16x8;
typedef __attribute__((ext_vector_type(4))) short bf16x4v;
typedef __attribute__((ext_vector_type(4))) float f32x4;

__device__ __forceinline__ short f2bf(float f) {
  union { float f; unsigned int u; } v; v.f = f;
  unsigned int u = v.u;
  u += 0x7fffu + ((u >> 16) & 1u);   // round-to-nearest-even
  return (short)(u >> 16);
}

#define GLOAD(gp, lp)                                               \
  __builtin_amdgcn_global_load_lds(                                 \
      (const __attribute__((address_space(1))) void*)(gp),          \
      (__attribute__((address_space(3))) void*)(lp), 16, 0, 0)

// ---------------------------------------------------------------------------
// init: zero the compaction counter (graph-capture-safe, no memset API)
// ---------------------------------------------------------------------------
__global__ void init_kernel(int* __restrict__ cnt) {
  if (threadIdx.x == 0) *cnt = 0;
}

// ---------------------------------------------------------------------------
// cvt2: fused fp32 -> bf16 for x and W1, 8 elems/thread, one launch
// ---------------------------------------------------------------------------
#define NX8 (M_TOT * K_TOT / 8)   // 1048576
#define NW8 (N_TOT * K_TOT / 8)   // 131072
__global__ __launch_bounds__(256) void cvt2_kernel(
    const float* __restrict__ x, short* __restrict__ xo,
    const float* __restrict__ w, short* __restrict__ wo) {
  int idx = blockIdx.x * 256 + threadIdx.x;
  const float* in; short* out; int k;
  if (idx < NX8)             { in = x; out = xo; k = idx; }
  else if (idx < NX8 + NW8)  { in = w; out = wo; k = idx - NX8; }
  else return;
  const float4* p = (const float4*)in + (size_t)k * 2;
  float4 a = p[0], b = p[1];
  bf16x8 v = { f2bf(a.x), f2bf(a.y), f2bf(a.z), f2bf(a.w),
               f2bf(b.x), f2bf(b.y), f2bf(b.z), f2bf(b.w) };
  *(bf16x8*)(out + (size_t)k * 8) = v;
}

// ---------------------------------------------------------------------------
// m97-structure bf16 GEMM: C[m,n] = sum_k A[m,k]*B[n,k] + (b0[n]+b1[n])
// A,B pre-converted bf16 row-major [*,1024]. 128x128 tile, BK=32,
// global_load_lds width 16, linear LDS, double-buffered.
// NOTE: wave fragment read covers 16 full 64B rows = 8 words/bank balanced;
// intra-row swizzle cannot improve it (analyzed r6) — keep linear.
// ---------------------------------------------------------------------------
__global__ __launch_bounds__(256) void gemm_bf16_kernel(
    const short* __restrict__ Ab, const short* __restrict__ Bb,
    const float* __restrict__ b0, const float* __restrict__ b1,
    float* __restrict__ C) {
  __shared__ short As[2][128 * 32];
  __shared__ short Bs[2][128 * 32];

  const int tid  = threadIdx.x;
  const int lane = tid & 63;
  const int w    = tid >> 6;
  const int wm   = w >> 1, wn = w & 1;

  // bijective XCD swizzle: nwg = 512, 512 % 8 == 0
  const int swz = (blockIdx.x & 7) * 64 + (blockIdx.x >> 3);
  const int bn  = swz & 7, bm = swz >> 3;

  const int l15 = lane & 15;
  const int kc  = (lane >> 4) << 3;      // 0,8,16,24

  const short* Abase = Ab + (size_t)bm * 128 * K_TOT;
  const short* Bbase = Bb + (size_t)bn * 128 * K_TOT;

  const int srow = tid >> 2;             // staging row within 64-row half
  const int scol = (tid & 3) << 3;       // k offset (bf16 elems), 16B each
  const int lbase = (tid & ~63) * 8;     // wave-uniform LDS elem base (+lane*8 by HW)

  f32x4 acc[4][4];
#pragma unroll
  for (int a = 0; a < 4; a++)
#pragma unroll
    for (int b = 0; b < 4; b++) {
      f32x4 z = {0.f, 0.f, 0.f, 0.f};
      acc[a][b] = z;
    }

#define STG(buf, k0)                                                        \
  {                                                                         \
    _Pragma("unroll")                                                       \
    for (int q = 0; q < 2; ++q) {                                           \
      GLOAD(Abase + (size_t)(q * 64 + srow) * K_TOT + (k0) + scol,          \
            &As[buf][q * 2048 + lbase]);                                    \
      GLOAD(Bbase + (size_t)(q * 64 + srow) * K_TOT + (k0) + scol,          \
            &Bs[buf][q * 2048 + lbase]);                                    \
    }                                                                       \
  }

  STG(0, 0);
  __syncthreads();

  const int NT = K_TOT / 32;  // 32
  for (int t = 0; t < NT; ++t) {
    const int cur = t & 1;
    if (t + 1 < NT) STG(cur ^ 1, (t + 1) * 32);

    bf16x8 af[4], bb[4];
#pragma unroll
    for (int mi = 0; mi < 4; ++mi)
      af[mi] = *(const bf16x8*)&As[cur][(wm * 64 + mi * 16 + l15) * 32 + kc];
#pragma unroll
    for (int ni = 0; ni < 4; ++ni)
      bb[ni] = *(const bf16x8*)&Bs[cur][(wn * 64 + ni * 16 + l15) * 32 + kc];

#pragma unroll
    for (int mi = 0; mi < 4; ++mi)
#pragma unroll
      for (int ni = 0; ni < 4; ++ni)
        acc[mi][ni] = __builtin_amdgcn_mfma_f32_16x16x32_bf16(
            af[mi], bb[ni], acc[mi][ni], 0, 0, 0);

    __syncthreads();   // drains vmcnt+lgkm; staged buffer ready, reads done
  }
#undef STG

#pragma unroll
  for (int ni = 0; ni < 4; ni++) {
    const int col = bn * 128 + wn * 64 + ni * 16 + l15;
    const float bias = b0[col] + b1[col];
#pragma unroll
    for (int mi = 0; mi < 4; mi++) {
      const int row0 = bm * 128 + wm * 64 + mi * 16 + ((lane >> 4) << 2);
#pragma unroll
      for (int r = 0; r < 4; r++)
        C[(size_t)(row0 + r) * N_TOT + col] = acc[mi][ni][r] + bias;
    }
  }
}

// ---------------------------------------------------------------------------
// fp32-staging GEMM fallback (round-1 kernel, validated)
// ---------------------------------------------------------------------------
#define BM 128
#define BN 128
#define BK 32
#define LDK 40

__global__ __launch_bounds__(256) void gemm_bias_kernel(
    const float* __restrict__ A, const float* __restrict__ Bw,
    const float* __restrict__ b0, const float* __restrict__ b1,
    float* __restrict__ C) {
  __shared__ short As[2][BM][LDK];
  __shared__ short Bs[2][BM][LDK];

  const int tid  = threadIdx.x;
  const int lane = tid & 63;
  const int w    = tid >> 6;
  const int wm   = w >> 1, wn = w & 1;
  const int bn   = blockIdx.x & 7;
  const int bm   = blockIdx.x >> 3;
  const int l15 = lane & 15;
  const int kc  = (lane >> 4) << 3;

  f32x4 acc[4][4];
#pragma unroll
  for (int a = 0; a < 4; a++)
#pragma unroll
    for (int b = 0; b < 4; b++) {
      f32x4 z = {0.f, 0.f, 0.f, 0.f};
      acc[a][b] = z;
    }

  const float* Abase = A  + (size_t)bm * BM * K_TOT;
  const float* Bbase = Bw + (size_t)bn * BN * K_TOT;
  float4 ra[4], rb[4];

#define LOADT(k0)                                                          \
  {                                                                        \
    _Pragma("unroll")                                                      \
    for (int q = 0; q < 4; q++) {                                          \
      int fidx = tid + q * 256;                                            \
      int r = fidx >> 3, cc = (fidx & 7) << 2;                             \
      ra[q] = *(const float4*)(Abase + (size_t)r * K_TOT + (k0) + cc);     \
      rb[q] = *(const float4*)(Bbase + (size_t)r * K_TOT + (k0) + cc);     \
    }                                                                      \
  }
#define STORET(buf)                                                        \
  {                                                                        \
    _Pragma("unroll")                                                      \
    for (int q = 0; q < 4; q++) {                                          \
      int fidx = tid + q * 256;                                            \
      int r = fidx >> 3, cc = (fidx & 7) << 2;                             \
      bf16x4v av = { f2bf(ra[q].x), f2bf(ra[q].y),                         \
                     f2bf(ra[q].z), f2bf(ra[q].w) };                       \
      bf16x4v bv = { f2bf(rb[q].x), f2bf(rb[q].y),                         \
                     f2bf(rb[q].z), f2bf(rb[q].w) };                       \
      *(bf16x4v*)&As[buf][r][cc] = av;                                     \
      *(bf16x4v*)&Bs[buf][r][cc] = bv;                                     \
    }                                                                      \
  }

  LOADT(0);
  STORET(0);
  __syncthreads();

  const int NT = K_TOT / BK;
  for (int t = 0; t < NT; ++t) {
    const int cur = t & 1;
    if (t + 1 < NT) LOADT((t + 1) * BK);
    bf16x8 af[4], bf_[4];
#pragma unroll
    for (int mi = 0; mi < 4; mi++)
      af[mi] = *(const bf16x8*)&As[cur][wm * 64 + mi * 16 + l15][kc];
#pragma unroll
    for (int ni = 0; ni < 4; ni++)
      bf_[ni] = *(const bf16x8*)&Bs[cur][wn * 64 + ni * 16 + l15][kc];
#pragma unroll
    for (int mi = 0; mi < 4; mi++)
#pragma unroll
      for (int ni = 0; ni < 4; ni++)
        acc[mi][ni] = __builtin_amdgcn_mfma_f32_16x16x32_bf16(
            af[mi], bf_[ni], acc[mi][ni], 0, 0, 0);
    if (t + 1 < NT) STORET(cur ^ 1);
    __syncthreads();
  }
#undef LOADT
#undef STORET

#pragma unroll
  for (int ni = 0; ni < 4; ni++) {
    const int col = bn * BN + wn * 64 + ni * 16 + l15;
    const float bias = b0[col] + b1[col];
#pragma unroll
    for (int mi = 0; mi < 4; mi++) {
      const int row0 = bm * BM + wm * 64 + mi * 16 + ((lane >> 4) << 2);
#pragma unroll
      for (int r = 0; r < 4; r++)
        C[(size_t)(row0 + r) * N_TOT + col] = acc[mi][ni][r] + bias;
    }
  }
}

// ---------------------------------------------------------------------------
// K2a scan: per (b,i) find bigram matches, average matched x rows,
// append (row_id, avg) to compact list in ws. Overflow -> direct atomic matvec.
// ---------------------------------------------------------------------------
__global__ __launch_bounds__(256) void scan_kernel(
    const int* __restrict__ ids, const float* __restrict__ x,
    int* __restrict__ cnt, int* __restrict__ rows, float* __restrict__ avg,
    const float* __restrict__ W0, float* __restrict__ y) {
  const int b = blockIdx.x >> 11;
  const int i = blockIdx.x & (S_LEN - 1);
  if (i < 3) return;

  const int* idb = ids + b * S_LEN;
  __shared__ int   s_cnt;
  __shared__ int   s_slot;
  __shared__ int   s_list[S_LEN];
  __shared__ float s_avg[DMODEL];

  const int tid = threadIdx.x;
  if (tid == 0) s_cnt = 0;
  __syncthreads();

  const int ti = idb[i], tp = idb[i - 1];
  for (int j = 2 + tid; j < i; j += 256) {
    if (idb[j - 1] == ti && idb[j - 2] == tp) {
      int p = atomicAdd(&s_cnt, 1);
      s_list[p] = j;
    }
  }
  __syncthreads();
  const int c = s_cnt;
  if (c == 0) return;

  float4 s = {0.f, 0.f, 0.f, 0.f};
  const float4* xb = (const float4*)(x + (size_t)b * S_LEN * DMODEL);
  for (int r = 0; r < c; ++r) {
    const int j = s_list[r];
    float4 v = xb[(size_t)j * (DMODEL / 4) + tid];
    s.x += v.x; s.y += v.y; s.z += v.z; s.w += v.w;
  }
  const float inv = 1.0f / (float)c;
  s.x *= inv; s.y *= inv; s.z *= inv; s.w *= inv;

  if (tid == 0) s_slot = atomicAdd(cnt, 1);
  __syncthreads();
  const int slot = s_slot;

  if (slot < MAXR) {
    if (tid == 0) rows[slot] = b * S_LEN + i;
    *(float4*)(avg + (size_t)slot * DMODEL + tid * 4) = s;
  } else {
    // overflow fallback: direct matvec, atomic accumulate (runs after GEMM)
    *(float4*)&s_avg[tid * 4] = s;
    __syncthreads();
    float* yrow = y + ((size_t)(b * S_LEN + i)) * DMODEL;
#pragma unroll
    for (int q = 0; q < 4; ++q) {
      const int n = q * 256 + tid;
      const float4* wr = (const float4*)(W0 + (size_t)n * DMODEL);
      float a = 0.f;
      for (int kk = 0; kk < DMODEL / 4; ++kk) {
        float4 wv = wr[kk];
        float4 av = *(const float4*)&s_avg[kk * 4];
        a += wv.x * av.x + wv.y * av.y + wv.z * av.z + wv.w * av.w;
      }
      atomicAdd(&yrow[n], a);
    }
  }
}

// ---------------------------------------------------------------------------
// K2b apply (v3): grid = RSLOTS x 16 col-groups (64 cols each).
// Block (r, cg): stage avg[r] in LDS; 4 threads per col, each does a
// 256-elem partial dot of W0[n,:]·avg[r], shuffle-4 reduce, one +=.
// Active blocks = R*16 (~512 for R~32): W0 traffic spread across CUs.
// Each (row,col) owned by exactly one block -> plain read-modify-write.
// ---------------------------------------------------------------------------
__global__ __launch_bounds__(256) void apply_kernel(
    const int* __restrict__ cnt, const int* __restrict__ rows,
    const float* __restrict__ avg, const float* __restrict__ W0,
    float* __restrict__ y) {
  int R = *cnt; if (R > MAXR) R = MAXR;
  const int rslot = blockIdx.x >> 4;         // 0..RSLOTS-1
  if (rslot >= R) return;                    // block-uniform early exit
  const int cg = blockIdx.x & 15;            // col group: 64 cols each
  const int tid = threadIdx.x;

  __shared__ float s_avg[DMODEL];

  for (int r = rslot; r < R; r += RSLOTS) {
    if (r != rslot) __syncthreads();         // protect LDS reuse
    *(float4*)&s_avg[tid * 4] =
        *(const float4*)(avg + (size_t)r * DMODEL + tid * 4);
    __syncthreads();

    const int n  = cg * 64 + (tid >> 2);     // output col
    const int ks = (tid & 3) * 256;          // k-slice of 256 floats
    const float4* wr = (const float4*)(W0 + (size_t)n * DMODEL + ks);
    const float4* ar = (const float4*)&s_avg[ks];
    float a = 0.f;
#pragma unroll 8
    for (int u = 0; u < 64; ++u) {
      float4 wv = wr[u], av = ar[u];
      a += wv.x * av.x + wv.y * av.y + wv.z * av.z + wv.w * av.w;
    }
    a += __shfl_down(a, 1, 4);
    a += __shfl_down(a, 2, 4);
    if ((tid & 3) == 0) {
      const int m = rows[r];
      y[(size_t)m * DMODEL + n] += a;
    }
  }
}

// ---------------------------------------------------------------------------
// round-1 induct kernel (ultra fallback, tiny ws)
// ---------------------------------------------------------------------------
__global__ __launch_bounds__(256) void induct_kernel(
    const int* __restrict__ ids, const float* __restrict__ x,
    const float* __restrict__ W0, float* __restrict__ y) {
  const int b = blockIdx.x >> 11;
  const int i = blockIdx.x & (S_LEN - 1);
  if (i < 3) return;
  const int* idb = ids + b * S_LEN;
  __shared__ int   s_cnt;
  __shared__ int   s_list[S_LEN];
  __shared__ float s_avg[DMODEL];
  const int tid = threadIdx.x;
  if (tid == 0) s_cnt = 0;
  __syncthreads();
  const int ti = idb[i], tp = idb[i - 1];
  for (int j = 2 + tid; j < i; j += 256) {
    if (idb[j - 1] == ti && idb[j - 2] == tp) {
      int p = atomicAdd(&s_cnt, 1);
      s_list[p] = j;
    }
  }
  __syncthreads();
  const int c = s_cnt;
  if (c == 0) return;
  float4 s = {0.f, 0.f, 0.f, 0.f};
  const float4* xb = (const float4*)(x + (size_t)b * S_LEN * DMODEL);
  for (int r = 0; r < c; ++r) {
    const int j = s_list[r];
    float4 v = xb[(size_t)j * (DMODEL / 4) + tid];
    s.x += v.x; s.y += v.y; s.z += v.z; s.w += v.w;
  }
  const float inv = 1.0f / (float)c;
  s.x *= inv; s.y *= inv; s.z *= inv; s.w *= inv;
  *(float4*)&s_avg[tid * 4] = s;
  __syncthreads();
  float out[4];
#pragma unroll
  for (int q = 0; q < 4; ++q) {
    const int n = q * 256 + tid;
    const float4* wr = (const float4*)(W0 + (size_t)n * DMODEL);
    float a = 0.f;
    for (int kk = 0; kk < DMODEL / 4; ++kk) {
      float4 wv = wr[kk];
      float4 av = *(const float4*)&s_avg[kk * 4];
      a += wv.x * av.x + wv.y * av.y + wv.z * av.z + wv.w * av.w;
    }
    out[q] = a;
  }
  float* yrow = y + ((size_t)(b * S_LEN + i)) * DMODEL;
#pragma unroll
  for (int q = 0; q < 4; ++q) yrow[q * 256 + tid] += out[q];
}

// ---------------------------------------------------------------------------
extern "C" void kernel_launch(void* const* d_in, const int* in_sizes, int n_in,
                              void* d_out, int out_size, void* d_ws, size_t ws_size,
                              hipStream_t stream) {
  const float* x   = (const float*)d_in[0];
  const int*   ids = (const int*)  d_in[1];
  const float* W0  = (const float*)d_in[2];
  const float* b0  = (const float*)d_in[3];
  const float* W1  = (const float*)d_in[4];
  const float* b1  = (const float*)d_in[5];
  float* y = (float*)d_out;

  char* ws = (char*)d_ws;
  int*   cnt  = (int*)(ws + CNT_OFF);
  int*   rows = (int*)(ws + ROWS_OFF);
  float* avg  = (float*)(ws + AVG_OFF);
  short* xbf  = (short*)(ws + XBF_OFF);
  short* wbf  = (short*)(ws + WBF_OFF);

  const bool full = ws_size >= FULL_NEED;
  const bool mid  = ws_size >= MID_NEED;

  if (full) {
    cvt2_kernel<<<(NX8 + NW8 + 255) / 256, 256, 0, stream>>>(x, xbf, W1, wbf);
    gemm_bf16_kernel<<<(M_TOT / 128) * (N_TOT / 128), 256, 0, stream>>>(xbf, wbf, b0, b1, y);
  } else {
    gemm_bias_kernel<<<(M_TOT / BM) * (N_TOT / BN), 256, 0, stream>>>(x, W1, b0, b1, y);
  }

  if (mid) {
    init_kernel<<<1, 64, 0, stream>>>(cnt);
    scan_kernel<<<BATCH * S_LEN, 256, 0, stream>>>(ids, x, cnt, rows, avg, W0, y);
    apply_kernel<<<RSLOTS * 16, 256, 0, stream>>>(cnt, rows, avg, W0, y);
  } else {
    induct_kernel<<<BATCH * S_LEN, 256, 0, stream>>>(ids, x, W0, y);
  }
}